// Round 2
// baseline (552.956 us; speedup 1.0000x reference)
//
#include <hip/hip_runtime.h>
#include <hip/hip_bf16.h>
#include <cmath>

#define NDIM  64
#define PSTR  72        // LDS plane row stride in f16 (144 B, 16B-aligned rows)
#define NDEG  19        // Chebyshev degree for log on [0.75, 8.75]; trunc err ~1.3e-6
#define TRI   2080      // 64*65/2
#define CMID  4.75f     // interval midpoint m; h = 4

struct Coeffs {
    float c[NDEG + 1];  // c'_k = sigma_k * c_k  (sigma = +,+,-,-,+,+,...)
};

typedef _Float16 f16x8 __attribute__((ext_vector_type(8)));
typedef _Float16 f16x4 __attribute__((ext_vector_type(4)));
typedef float    f32x4 __attribute__((ext_vector_type(4)));

// SPD => symmetric under the TRUE dtype; wrong reinterpretation gives O(1)/NaN residual.
__device__ __forceinline__ bool sniff_is_bf16(const void* xin)
{
    const float*          f0 = (const float*)xin;
    const unsigned short* h0 = (const unsigned short*)xin;
    const int pi[8] = {1, 3, 5, 2, 4, 6, 7, 8};
    const int pj[8] = {2, 7, 11, 9, 13, 17, 23, 31};
    float fsym = 0.f, bsym = 0.f;
    #pragma unroll
    for (int p = 0; p < 8; ++p) {
        const int i = pi[p], j = pj[p];
        fsym += fabsf(f0[i * NDIM + j] - f0[j * NDIM + i]);
        union { unsigned u; float f; } ua, ub;
        ua.u = ((unsigned)h0[i * NDIM + j]) << 16;
        ub.u = ((unsigned)h0[j * NDIM + i]) << 16;
        bsym += fabsf(ua.f - ub.f);
    }
    if (fsym != fsym) return true;
    if (bsym != bsym) return false;
    return bsym < fsym;
}

// One 64x64 matrix per 256-thread block (4 waves); wave w owns the 32x32 output
// quadrant (m_base=(w&1)*32, n_base=(w>>1)*32) as 2x2 mfma_f32_16x16x32_f16 tiles.
//
// Recurrence with A2 = (X - mI)/2 (EXACT in f16 for bf16 input):
//   T_k = A2*T_{k-1} - T_{k-2}
// Signed variables V_k = sigma_k T_k (sigma period 4: +,+,-,-) and LDS planes
// holding rho_k V_k (rho_k = -1 for odd k) make every step a single in-place
//   set = mfma(A2, plane, set)
// with C-in = V_{k-2} and D-out = V_k: no recurrence VALU at all. Signs are
// folded into host coefficients (c'_k) and the f16-convert of the plane write.
#define CHEB_STEP(SET, RP, WP, CK, NEGW, DOW)                                         \
    {                                                                                 \
        f16x8 bfr[2][2];                                                              \
        _Pragma("unroll") for (int nt = 0; nt < 2; ++nt)                              \
            _Pragma("unroll") for (int kt = 0; kt < 2; ++kt)                          \
                bfr[nt][kt] = *(const f16x8*)&(RP)[(n_base + nt * 16 + l) * PSTR + kt * 32 + q * 8]; \
        _Pragma("unroll") for (int mt = 0; mt < 2; ++mt) {                            \
            const int mrow0 = m_base + mt * 16 + q * 4;                               \
            _Pragma("unroll") for (int nt = 0; nt < 2; ++nt) {                        \
                f32x4 acc = SET[mt][nt];                                              \
                acc = __builtin_amdgcn_mfma_f32_16x16x32_f16(afrag[mt][0], bfr[nt][0], acc, 0, 0, 0); \
                acc = __builtin_amdgcn_mfma_f32_16x16x32_f16(afrag[mt][1], bfr[nt][1], acc, 0, 0, 0); \
                SET[mt][nt] = acc;                                                    \
                yacc[mt][nt] += (CK) * acc;                                           \
                if (DOW) {                                                            \
                    const int ncol = n_base + nt * 16 + l;                            \
                    f16x4 w;                                                          \
                    _Pragma("unroll") for (int r = 0; r < 4; ++r)                     \
                        w[r] = (_Float16)((NEGW) ? -acc[r] : acc[r]);                 \
                    *(f16x4*)&(WP)[ncol * PSTR + mrow0] = w;                          \
                }                                                                     \
            }                                                                         \
        }                                                                             \
    }

__global__ __launch_bounds__(256, 4)
void spd_log_mfma(const void* __restrict__ xin,
                  float* __restrict__ out,
                  Coeffs co)
{
    __shared__ __align__(16) _Float16 planes[2][NDIM * PSTR];   // 2 x 9216 B

    const int b    = blockIdx.x;
    const int tid  = threadIdx.x;
    const int wave = tid >> 6;
    const int lane = tid & 63;
    const int l    = lane & 15;     // fragment col (n) / A row (m) index
    const int q    = lane >> 4;     // quad
    const int m_base = (wave & 1) * 32;
    const int n_base = (wave >> 1) * 32;

    const bool isb = sniff_is_bf16(xin);

    // ---------------- stage: plane0 = A2 = (X-mI)/2, plane1 = -A2/2 = -T1 ----------------
    // Both are EXACT f16 for bf16 input (grid argument on the diagonal; exponent
    // shifts elsewhere).
    if (isb) {
        const uint2* xv = (const uint2*)((const unsigned short*)xin + (size_t)b * (NDIM * NDIM));
        #pragma unroll
        for (int r = 0; r < 4; ++r) {
            const int e4 = tid + r * 256;          // 1024 quads
            const int e0 = e4 * 4;
            const int row = e0 >> 6, col = e0 & 63;
            const uint2 w = xv[e4];
            union { unsigned u; float f; } c0, c1, c2, c3;
            c0.u = (w.x & 0xffffu) << 16; c1.u = (w.x & 0xffff0000u);
            c2.u = (w.y & 0xffffu) << 16; c3.u = (w.y & 0xffff0000u);
            float v[4] = {c0.f, c1.f, c2.f, c3.f};
            const int dj = row - col;
            if ((unsigned)dj < 4u) v[dj] -= CMID;
            f16x4 h0, h1;
            #pragma unroll
            for (int j = 0; j < 4; ++j) {
                const float a2 = v[j] * 0.5f;
                h0[j] = (_Float16)a2;
                h1[j] = (_Float16)(-0.5f * a2);
            }
            *(f16x4*)&planes[0][row * PSTR + col] = h0;
            *(f16x4*)&planes[1][row * PSTR + col] = h1;
        }
    } else {
        const float4* xv = (const float4*)((const float*)xin + (size_t)b * (NDIM * NDIM));
        #pragma unroll
        for (int r = 0; r < 4; ++r) {
            const int e4 = tid + r * 256;
            const int e0 = e4 * 4;
            const int row = e0 >> 6, col = e0 & 63;
            const float4 w = xv[e4];
            float v[4] = {w.x, w.y, w.z, w.w};
            const int dj = row - col;
            if ((unsigned)dj < 4u) v[dj] -= CMID;
            f16x4 h0, h1;
            #pragma unroll
            for (int j = 0; j < 4; ++j) {
                const float a2 = v[j] * 0.5f;
                h0[j] = (_Float16)a2;
                h1[j] = (_Float16)(-0.5f * a2);
            }
            *(f16x4*)&planes[0][row * PSTR + col] = h0;
            *(f16x4*)&planes[1][row * PSTR + col] = h1;
        }
    }
    __syncthreads();

    // ---------------- A-fragments: A2[m][k], fixed all steps ----------------
    f16x8 afrag[2][2];
    #pragma unroll
    for (int mt = 0; mt < 2; ++mt)
        #pragma unroll
        for (int kt = 0; kt < 2; ++kt)
            afrag[mt][kt] = *(const f16x8*)&planes[0][(m_base + mt * 16 + l) * PSTR + kt * 32 + q * 8];

    // ---------------- init register state in C/D layout ----------------
    // set0 = V0 = I, set1 = V1 = T1 (negated read of plane1), yacc = c'0*I + c'1*T1
    f32x4 set0[2][2], set1[2][2], yacc[2][2];
    #pragma unroll
    for (int mt = 0; mt < 2; ++mt) {
        const int mrow0 = m_base + mt * 16 + q * 4;
        #pragma unroll
        for (int nt = 0; nt < 2; ++nt) {
            const int ncol = n_base + nt * 16 + l;
            const f16x4 tv = *(const f16x4*)&planes[1][ncol * PSTR + mrow0]; // = -T1 (symmetric)
            #pragma unroll
            for (int r = 0; r < 4; ++r) {
                const bool diag = (mrow0 + r) == ncol;
                const float t1 = -(float)tv[r];
                set1[mt][nt][r] = t1;
                set0[mt][nt][r] = diag ? 1.f : 0.f;
                yacc[mt][nt][r] = co.c[1] * t1 + (diag ? co.c[0] : 0.f);
            }
        }
    }
    __syncthreads();   // afrag/set1 plane reads done before k=2 writes plane0

    // ---------------- Chebyshev recurrence, unrolled by 2 ----------------
    // even k: set0 = mfma(A2, plane1, set0) = V_k, write +V_k -> plane0
    // odd  k: set1 = mfma(A2, plane0, set1) = V_k, write -V_k -> plane1
    for (int kk = 2; kk < NDEG; kk += 2) {
        CHEB_STEP(set0, planes[1], planes[0], co.c[kk], false, true);
        __syncthreads();
        const bool wr = (kk + 1) < NDEG;   // last odd step feeds nothing
        CHEB_STEP(set1, planes[0], planes[1], co.c[kk + 1], true, wr);
        __syncthreads();
    }

    // ---------------- output: stage triu in LDS, then coalesced fp32 stores ----------------
    float* ybuf = (float*)&planes[0][0];    // 8320 B <= 9216 B of plane0
    #pragma unroll
    for (int mt = 0; mt < 2; ++mt) {
        const int mrow0 = m_base + mt * 16 + q * 4;
        #pragma unroll
        for (int nt = 0; nt < 2; ++nt) {
            const int ncol = n_base + nt * 16 + l;
            #pragma unroll
            for (int r = 0; r < 4; ++r) {
                const int m = mrow0 + r;
                if (m <= ncol)
                    ybuf[m * NDIM - (m * (m - 1)) / 2 + (ncol - m)] = yacc[mt][nt][r];
            }
        }
    }
    __syncthreads();

    float4* dst = (float4*)(out + (size_t)b * TRI);
    const float4* src = (const float4*)ybuf;
    for (int e = tid; e < TRI / 4; e += 256)
        dst[e] = src[e];
}

extern "C" void kernel_launch(void* const* d_in, const int* in_sizes, int n_in,
                              void* d_out, int out_size, void* d_ws, size_t ws_size,
                              hipStream_t stream)
{
    (void)n_in; (void)d_ws; (void)ws_size; (void)out_size;

    // Chebyshev coefficients of log on [a,b] = [0.75, 8.75]:
    // log(m + h t) = log(h/(2g)) + sum_{k>=1} 2(-1)^{k+1} g^k / k * T_k(t)
    // h = 4 (power of two), m = 4.75. Signs sigma_k (period 4: +,+,-,-) folded in.
    const double a = 0.75, bnd = 8.75;
    const double m = 0.5 * (a + bnd), h = 0.5 * (bnd - a);
    const double alpha = h / m;
    const double gam = (1.0 - sqrt(1.0 - alpha * alpha)) / alpha;

    Coeffs co;
    co.c[0] = (float)log(h / (2.0 * gam));
    double g = 1.0;
    for (int k = 1; k <= NDEG; ++k) {
        g *= gam;
        const double ck  = (((k & 1) ? 2.0 : -2.0) * g) / (double)k;
        const double sig = ((k >> 1) & 1) ? -1.0 : 1.0;
        co.c[k] = (float)(ck * sig);
    }

    const int B = in_sizes[0] / (NDIM * NDIM);
    spd_log_mfma<<<B, 256, 0, stream>>>(d_in[0], (float*)d_out, co);
}

// Round 5
// 248.147 us; speedup vs baseline: 2.2283x; 2.2283x over previous
//
#include <hip/hip_runtime.h>
#include <hip/hip_bf16.h>
#include <cmath>

#define NDIM  64
#define PSTR  72        // LDS plane row stride in f16 (144 B, 16B-aligned rows)
#define NDEG  19        // Chebyshev degree for log on [0.75, 8.75]; trunc err ~1.3e-6
#define TRI   2080      // 64*65/2
#define CMID  4.75f     // interval midpoint m; h = 4

struct Coeffs {
    float c[NDEG + 1];  // c'_k = sigma_k * c_k  (sigma = +,+,-,-,+,+,...)
};

typedef _Float16 f16x8 __attribute__((ext_vector_type(8)));
typedef _Float16 f16x4 __attribute__((ext_vector_type(4)));
typedef float    f32x4 __attribute__((ext_vector_type(4)));

// SPD => symmetric under the TRUE dtype; wrong reinterpretation gives O(1)/NaN residual.
__device__ __forceinline__ bool sniff_is_bf16(const void* xin)
{
    const float*          f0 = (const float*)xin;
    const unsigned short* h0 = (const unsigned short*)xin;
    const int pi[8] = {1, 3, 5, 2, 4, 6, 7, 8};
    const int pj[8] = {2, 7, 11, 9, 13, 17, 23, 31};
    float fsym = 0.f, bsym = 0.f;
    #pragma unroll
    for (int p = 0; p < 8; ++p) {
        const int i = pi[p], j = pj[p];
        fsym += fabsf(f0[i * NDIM + j] - f0[j * NDIM + i]);
        union { unsigned u; float f; } ua, ub;
        ua.u = ((unsigned)h0[i * NDIM + j]) << 16;
        ub.u = ((unsigned)h0[j * NDIM + i]) << 16;
        bsym += fabsf(ua.f - ub.f);
    }
    if (fsym != fsym) return true;
    if (bsym != bsym) return false;
    return bsym < fsym;
}

// One 64x64 matrix per 256-thread block (4 waves); wave w owns the 32x32 output
// quadrant (m_base=(w&1)*32, n_base=(w>>1)*32) as 2x2 mfma_f32_16x16x32_f16 tiles.
//
// Recurrence with A2 = (X - mI)/2 (EXACT in f16 for bf16 input):
//   T_k = A2*T_{k-1} - T_{k-2}
// Signed variables V_k = sigma_k T_k (sigma period 4: +,+,-,-) and LDS planes
// holding rho_k*V_{k-1} (rho = -1 for even k) make every step a single in-place
//   set = mfma(A2, plane, set)          // C-in = V_{k-2}, D-out = V_k
// with no recurrence VALU. Signs are folded into host coefficients c'_k and the
// sign of the f16 plane-write.
//
// Scratch discipline (rule #20, round-2 lesson): ALL persistent state is
// individually named; ALL vector component accesses use literal indices;
// no pragma-loops inside macros.

#define PK4(W, S, SGN)                                                    \
    { W[0] = (_Float16)(SGN S[0]); W[1] = (_Float16)(SGN S[1]);           \
      W[2] = (_Float16)(SGN S[2]); W[3] = (_Float16)(SGN S[3]); }

// One Chebyshev step for one register set (4 tiles), reading plane RP,
// writing plane WP with sign SGN. Named variables only.
#define CHEB_STEP(S00, S01, S10, S11, RP, WP, CK, SGN)                           \
    {                                                                            \
        const f16x8 b00 = *(const f16x8*)&(RP)[nrow0 + qo];                      \
        const f16x8 b01 = *(const f16x8*)&(RP)[nrow0 + 32 + qo];                 \
        const f16x8 b10 = *(const f16x8*)&(RP)[nrow1 + qo];                      \
        const f16x8 b11 = *(const f16x8*)&(RP)[nrow1 + 32 + qo];                 \
        S00 = __builtin_amdgcn_mfma_f32_16x16x32_f16(a00, b00, S00, 0, 0, 0);    \
        S00 = __builtin_amdgcn_mfma_f32_16x16x32_f16(a01, b01, S00, 0, 0, 0);    \
        S01 = __builtin_amdgcn_mfma_f32_16x16x32_f16(a00, b10, S01, 0, 0, 0);    \
        S01 = __builtin_amdgcn_mfma_f32_16x16x32_f16(a01, b11, S01, 0, 0, 0);    \
        S10 = __builtin_amdgcn_mfma_f32_16x16x32_f16(a10, b00, S10, 0, 0, 0);    \
        S10 = __builtin_amdgcn_mfma_f32_16x16x32_f16(a11, b01, S10, 0, 0, 0);    \
        S11 = __builtin_amdgcn_mfma_f32_16x16x32_f16(a10, b10, S11, 0, 0, 0);    \
        S11 = __builtin_amdgcn_mfma_f32_16x16x32_f16(a11, b11, S11, 0, 0, 0);    \
        const float ck_ = (CK);                                                  \
        y00 += ck_ * S00; y01 += ck_ * S01;                                      \
        y10 += ck_ * S10; y11 += ck_ * S11;                                      \
        f16x4 w_;                                                                \
        PK4(w_, S00, SGN) *(f16x4*)&(WP)[nc0 * PSTR + mrow0] = w_;               \
        PK4(w_, S01, SGN) *(f16x4*)&(WP)[nc1 * PSTR + mrow0] = w_;               \
        PK4(w_, S10, SGN) *(f16x4*)&(WP)[nc0 * PSTR + mrow1] = w_;               \
        PK4(w_, S11, SGN) *(f16x4*)&(WP)[nc1 * PSTR + mrow1] = w_;               \
    }

#define TRIW1(Y, R, MR, NC)                                                      \
    { const int m_ = (MR) + (R);                                                 \
      if (m_ <= (NC)) ybuf[m_ * NDIM - (m_ * (m_ - 1)) / 2 + ((NC) - m_)] = Y[R]; }
#define TRIW(Y, MR, NC) \
    TRIW1(Y, 0, MR, NC) TRIW1(Y, 1, MR, NC) TRIW1(Y, 2, MR, NC) TRIW1(Y, 3, MR, NC)

__global__ __launch_bounds__(256, 4)
void spd_log_mfma(const void* __restrict__ xin,
                  float* __restrict__ out,
                  Coeffs co)
{
    __shared__ __align__(16) _Float16 planes[2][NDIM * PSTR];   // 2 x 9216 B

    const int b    = blockIdx.x;
    const int tid  = threadIdx.x;
    const int wave = tid >> 6;
    const int lane = tid & 63;
    const int l    = lane & 15;     // fragment col (n) / A row (m) index
    const int q    = lane >> 4;     // quad
    const int qo   = q * 8;
    const int m_base = (wave & 1) * 32;
    const int n_base = (wave >> 1) * 32;

    _Float16* const p0 = &planes[0][0];
    _Float16* const p1 = &planes[1][0];

    const bool isb = sniff_is_bf16(xin);

    // ---------------- stage: p0 = A2 = (X-mI)/2, p1 = -A2/2 = -T1 ----------------
    // Both EXACT in f16 for bf16 input (shared 2^-8 grid on the diagonal;
    // exponent shifts elsewhere). Diagonal fix via literal-index ternaries.
    if (isb) {
        const uint2* xv = (const uint2*)((const unsigned short*)xin + (size_t)b * (NDIM * NDIM));
        #pragma unroll
        for (int r = 0; r < 4; ++r) {
            const int e4 = tid + r * 256;          // 1024 quads
            const int e0 = e4 * 4;
            const int row = e0 >> 6, col = e0 & 63;
            const uint2 w = xv[e4];
            union { unsigned u; float f; } u0, u1, u2, u3;
            u0.u = (w.x & 0xffffu) << 16; u1.u = (w.x & 0xffff0000u);
            u2.u = (w.y & 0xffffu) << 16; u3.u = (w.y & 0xffff0000u);
            const float v0 = u0.f - ((col + 0 == row) ? CMID : 0.f);
            const float v1 = u1.f - ((col + 1 == row) ? CMID : 0.f);
            const float v2 = u2.f - ((col + 2 == row) ? CMID : 0.f);
            const float v3 = u3.f - ((col + 3 == row) ? CMID : 0.f);
            f16x4 h0, h1;
            h0[0] = (_Float16)(v0 * 0.5f);   h0[1] = (_Float16)(v1 * 0.5f);
            h0[2] = (_Float16)(v2 * 0.5f);   h0[3] = (_Float16)(v3 * 0.5f);
            h1[0] = (_Float16)(v0 * -0.25f); h1[1] = (_Float16)(v1 * -0.25f);
            h1[2] = (_Float16)(v2 * -0.25f); h1[3] = (_Float16)(v3 * -0.25f);
            *(f16x4*)&p0[row * PSTR + col] = h0;
            *(f16x4*)&p1[row * PSTR + col] = h1;
        }
    } else {
        const float4* xv = (const float4*)((const float*)xin + (size_t)b * (NDIM * NDIM));
        #pragma unroll
        for (int r = 0; r < 4; ++r) {
            const int e4 = tid + r * 256;
            const int e0 = e4 * 4;
            const int row = e0 >> 6, col = e0 & 63;
            const float4 w = xv[e4];
            const float v0 = w.x - ((col + 0 == row) ? CMID : 0.f);
            const float v1 = w.y - ((col + 1 == row) ? CMID : 0.f);
            const float v2 = w.z - ((col + 2 == row) ? CMID : 0.f);
            const float v3 = w.w - ((col + 3 == row) ? CMID : 0.f);
            f16x4 h0, h1;
            h0[0] = (_Float16)(v0 * 0.5f);   h0[1] = (_Float16)(v1 * 0.5f);
            h0[2] = (_Float16)(v2 * 0.5f);   h0[3] = (_Float16)(v3 * 0.5f);
            h1[0] = (_Float16)(v0 * -0.25f); h1[1] = (_Float16)(v1 * -0.25f);
            h1[2] = (_Float16)(v2 * -0.25f); h1[3] = (_Float16)(v3 * -0.25f);
            *(f16x4*)&p0[row * PSTR + col] = h0;
            *(f16x4*)&p1[row * PSTR + col] = h1;
        }
    }
    __syncthreads();

    // ---------------- A-fragments: A2[m][k], fixed all steps (named) ----------------
    const int arow0 = (m_base + l) * PSTR;
    const int arow1 = (m_base + 16 + l) * PSTR;
    const f16x8 a00 = *(const f16x8*)&p0[arow0 + qo];
    const f16x8 a01 = *(const f16x8*)&p0[arow0 + 32 + qo];
    const f16x8 a10 = *(const f16x8*)&p0[arow1 + qo];
    const f16x8 a11 = *(const f16x8*)&p0[arow1 + 32 + qo];

    // B-fragment row offsets / store coordinates, reused every step
    const int nrow0 = (n_base + l) * PSTR;
    const int nrow1 = (n_base + 16 + l) * PSTR;
    const int nc0   = n_base + l;
    const int nc1   = n_base + 16 + l;
    const int mrow0 = m_base + q * 4;
    const int mrow1 = m_base + 16 + q * 4;

    // ---------------- init register state in C/D layout (named) ----------------
    // set0 = V0 = I, set1 = V1 = T1 (negated read of p1 = -T1), y = c'0*I + c'1*T1
    const float cc0 = co.c[0], cc1 = co.c[1];
    f32x4 s0_00, s0_01, s0_10, s0_11;
    f32x4 s1_00, s1_01, s1_10, s1_11;
    f32x4 y00, y01, y10, y11;

#define INIT_TILE(S1, S0, Y, MR, NC)                                             \
    {                                                                            \
        const f16x4 tv = *(const f16x4*)&p1[(NC) * PSTR + (MR)];                 \
        S1[0] = -(float)tv[0]; S1[1] = -(float)tv[1];                            \
        S1[2] = -(float)tv[2]; S1[3] = -(float)tv[3];                            \
        S0[0] = ((MR) + 0 == (NC)) ? 1.f : 0.f;                                  \
        S0[1] = ((MR) + 1 == (NC)) ? 1.f : 0.f;                                  \
        S0[2] = ((MR) + 2 == (NC)) ? 1.f : 0.f;                                  \
        S0[3] = ((MR) + 3 == (NC)) ? 1.f : 0.f;                                  \
        Y[0] = cc1 * S1[0] + cc0 * S0[0]; Y[1] = cc1 * S1[1] + cc0 * S0[1];      \
        Y[2] = cc1 * S1[2] + cc0 * S0[2]; Y[3] = cc1 * S1[3] + cc0 * S0[3];      \
    }
    INIT_TILE(s1_00, s0_00, y00, mrow0, nc0)
    INIT_TILE(s1_01, s0_01, y01, mrow0, nc1)
    INIT_TILE(s1_10, s0_10, y10, mrow1, nc0)
    INIT_TILE(s1_11, s0_11, y11, mrow1, nc1)
#undef INIT_TILE
    __syncthreads();   // afrag/init plane reads done before k=2 overwrites p0

    // ---------------- Chebyshev recurrence, two steps per iteration ----------------
    // even k: set0 = mfma(A2, p1, set0) = V_k, write +V_k -> p0
    // odd  k: set1 = mfma(A2, p0, set1) = V_k, write -V_k -> p1
    for (int kk = 2; kk < NDEG; kk += 2) {
        CHEB_STEP(s0_00, s0_01, s0_10, s0_11, p1, p0, co.c[kk], +)
        __syncthreads();
        CHEB_STEP(s1_00, s1_01, s1_10, s1_11, p0, p1, co.c[kk + 1], -)
        __syncthreads();
    }

    // ---------------- output: stage triu in LDS, then coalesced fp32 stores ----------------
    float* ybuf = (float*)p0;      // 8320 B <= 9216 B of plane0
    TRIW(y00, mrow0, nc0)
    TRIW(y01, mrow0, nc1)
    TRIW(y10, mrow1, nc0)
    TRIW(y11, mrow1, nc1)
    __syncthreads();

    float4* dst = (float4*)(out + (size_t)b * TRI);
    const float4* src = (const float4*)ybuf;
    for (int e = tid; e < TRI / 4; e += 256)
        dst[e] = src[e];
}

extern "C" void kernel_launch(void* const* d_in, const int* in_sizes, int n_in,
                              void* d_out, int out_size, void* d_ws, size_t ws_size,
                              hipStream_t stream)
{
    (void)n_in; (void)d_ws; (void)ws_size; (void)out_size;

    // Chebyshev coefficients of log on [a,b] = [0.75, 8.75]:
    // log(m + h t) = log(h/(2g)) + sum_{k>=1} 2(-1)^{k+1} g^k / k * T_k(t)
    // h = 4 (power of two), m = 4.75. Signs sigma_k (period 4: +,+,-,-) folded in.
    const double a = 0.75, bnd = 8.75;
    const double m = 0.5 * (a + bnd), h = 0.5 * (bnd - a);
    const double alpha = h / m;
    const double gam = (1.0 - sqrt(1.0 - alpha * alpha)) / alpha;

    Coeffs co;
    co.c[0] = (float)log(h / (2.0 * gam));
    double g = 1.0;
    for (int k = 1; k <= NDEG; ++k) {
        g *= gam;
        const double ck  = (((k & 1) ? 2.0 : -2.0) * g) / (double)k;
        const double sig = ((k >> 1) & 1) ? -1.0 : 1.0;
        co.c[k] = (float)(ck * sig);
    }

    const int B = in_sizes[0] / (NDIM * NDIM);
    spd_log_mfma<<<B, 256, 0, stream>>>(d_in[0], (float*)d_out, co);
}